// Round 1
// baseline (912.185 us; speedup 1.0000x reference)
//
#include <hip/hip_runtime.h>
#include <stdint.h>

// GeoAwarePooling: B=4, N=40000, C=128, V=4 views.
// Key insight: xyz is broadcast across the 4 views, so local_xyz / global_xyz /
// weights are view-independent. Per-point MLP runs over B*N points only.

#define NPTS 40000
#define CDIM 128

__device__ __forceinline__ float wredsum(float v) {
#pragma unroll
  for (int o = 32; o > 0; o >>= 1) v += __shfl_xor(v, o);
  return v;
}
__device__ __forceinline__ unsigned short f2bf(float f) {
  unsigned u = __float_as_uint(f);
  u += 0x7FFFu + ((u >> 16) & 1u);  // RNE
  return (unsigned short)(u >> 16);
}
__device__ __forceinline__ float bf2f(unsigned short s) {
  return __uint_as_float(((unsigned)s) << 16);
}
// order-preserving float->uint key for atomicMax over signed floats
__device__ __forceinline__ unsigned fenc(float f) {
  unsigned u = __float_as_uint(f);
  return (u & 0x80000000u) ? ~u : (u | 0x80000000u);
}
__device__ __forceinline__ float fdec(unsigned k) {
  return (k & 0x80000000u) ? __uint_as_float(k & 0x7FFFFFFFu)
                           : __uint_as_float(~k);
}

__global__ void k_init(unsigned* __restrict__ gkey, float* __restrict__ denom) {
  int t = threadIdx.x;
  if (t < 512) gkey[t] = 0u;  // fdec(0)=NaN but always overwritten (40000 pts)
  if (t < 16) denom[t] = 0.f;
}

// Phase 1: y = xyz@W1+b1; h = relu(LN(y)); local = LN(h@W2+b2)
// one wave per point, lane owns channels (2l, 2l+1)
__global__ __launch_bounds__(256) void k_phase1(
    const float* __restrict__ xyz, const float* __restrict__ W1,
    const float* __restrict__ b1, const float* __restrict__ g1,
    const float* __restrict__ be1, const float* __restrict__ W2,
    const float* __restrict__ b2, const float* __restrict__ g2,
    const float* __restrict__ be2, unsigned* __restrict__ gkey,
    unsigned short* __restrict__ localw) {
  __shared__ float w2s[CDIM * CDIM];  // 64 KiB
  for (int i = threadIdx.x; i < CDIM * CDIM / 4; i += 256)
    reinterpret_cast<float4*>(w2s)[i] = reinterpret_cast<const float4*>(W2)[i];
  __syncthreads();

  const int b = blockIdx.x >> 8;      // 256 blocks per batch
  const int ib = blockIdx.x & 255;
  const int wave = threadIdx.x >> 6;
  const int lane = threadIdx.x & 63;
  const int c0 = 2 * lane;

  // per-lane weight/param pairs
  float2 w1r0 = *(const float2*)&W1[0 * CDIM + c0];
  float2 w1r1 = *(const float2*)&W1[1 * CDIM + c0];
  float2 w1r2 = *(const float2*)&W1[2 * CDIM + c0];
  float2 b1v = *(const float2*)&b1[c0];
  float2 g1v = *(const float2*)&g1[c0];
  float2 be1v = *(const float2*)&be1[c0];
  float2 b2v = *(const float2*)&b2[c0];
  float2 g2v = *(const float2*)&g2[c0];
  float2 be2v = *(const float2*)&be2[c0];

  float m0 = -1e30f, m1 = -1e30f;

  for (int n = ib * 4 + wave; n < NPTS; n += 1024) {
    const float px = xyz[(b * 3 + 0) * NPTS + n];
    const float py = xyz[(b * 3 + 1) * NPTS + n];
    const float pz = xyz[(b * 3 + 2) * NPTS + n];
    float y0 = px * w1r0.x + py * w1r1.x + pz * w1r2.x + b1v.x;
    float y1 = px * w1r0.y + py * w1r1.y + pz * w1r2.y + b1v.y;
    // LN1
    float S1 = wredsum(y0 + y1);
    float S2 = wredsum(y0 * y0 + y1 * y1);
    float mu = S1 * (1.f / 128.f);
    float var = S2 * (1.f / 128.f) - mu * mu;
    float rs = rsqrtf(var + 1e-5f);
    float h0 = fmaxf(0.f, (y0 - mu) * rs * g1v.x + be1v.x);
    float h1 = fmaxf(0.f, (y1 - mu) * rs * g1v.y + be1v.y);
    // h @ W2 + b2 ; h[2j], h[2j+1] live on lane j
    float a0 = b2v.x, a1 = b2v.y;
#pragma unroll 8
    for (int j = 0; j < 64; ++j) {
      float hk0 = __shfl(h0, j);
      float hk1 = __shfl(h1, j);
      float2 wA = *(const float2*)&w2s[(2 * j) * CDIM + c0];
      float2 wB = *(const float2*)&w2s[(2 * j + 1) * CDIM + c0];
      a0 += hk0 * wA.x + hk1 * wB.x;
      a1 += hk0 * wA.y + hk1 * wB.y;
    }
    // LN2
    float T1 = wredsum(a0 + a1);
    float T2 = wredsum(a0 * a0 + a1 * a1);
    float mu2 = T1 * (1.f / 128.f);
    float var2 = T2 * (1.f / 128.f) - mu2 * mu2;
    float rs2 = rsqrtf(var2 + 1e-5f);
    float l0 = (a0 - mu2) * rs2 * g2v.x + be2v.x;
    float l1 = (a1 - mu2) * rs2 * g2v.y + be2v.y;
    m0 = fmaxf(m0, l0);
    m1 = fmaxf(m1, l1);
    unsigned pk = ((unsigned)f2bf(l0)) | (((unsigned)f2bf(l1)) << 16);
    *reinterpret_cast<unsigned*>(&localw[(size_t)(b * NPTS + n) * CDIM + c0]) = pk;
  }

  // block max reduce: reuse w2s
  __syncthreads();
  float* red = w2s;
  red[(wave * 64 + lane) * 2 + 0] = m0;
  red[(wave * 64 + lane) * 2 + 1] = m1;
  __syncthreads();
  if (wave == 0) {
    float M0 = fmaxf(fmaxf(red[lane * 2], red[(64 + lane) * 2]),
                     fmaxf(red[(128 + lane) * 2], red[(192 + lane) * 2]));
    float M1 = fmaxf(fmaxf(red[lane * 2 + 1], red[(64 + lane) * 2 + 1]),
                     fmaxf(red[(128 + lane) * 2 + 1], red[(192 + lane) * 2 + 1]));
    atomicMax(&gkey[b * CDIM + c0], fenc(M0));
    atomicMax(&gkey[b * CDIM + c0 + 1], fenc(M1));
  }
}

// decode global max; gproj[b,c] = sum_k global[b,k] * W3[128+k, c]
__global__ void k_global(const unsigned* __restrict__ gkey,
                         const float* __restrict__ W3,
                         float* __restrict__ globalv,
                         float* __restrict__ gproj) {
  __shared__ float gs[512];
  int t = threadIdx.x;  // 512 threads
  float g = fdec(gkey[t]);
  gs[t] = g;
  globalv[t] = g;
  __syncthreads();
  int b = t >> 7, c = t & 127;
  float acc = 0.f;
  for (int k = 0; k < CDIM; ++k)
    acc += gs[b * CDIM + k] * W3[(CDIM + k) * CDIM + c];
  gproj[t] = acc;
}

// Phase 2: u = local@W3top + gproj + b3; h2 = relu(LN(u)); w = 2*sigmoid(h2@W4)
__global__ __launch_bounds__(256) void k_phase2(
    const unsigned short* __restrict__ localw, const float* __restrict__ gproj,
    const float* __restrict__ W3, const float* __restrict__ b3,
    const float* __restrict__ g3, const float* __restrict__ be3,
    const float* __restrict__ W4, const float* __restrict__ masks,
    float* __restrict__ w_arr, float* __restrict__ denom) {
  __shared__ float w3s[CDIM * CDIM];  // top half of W3 (rows 0..127), 64 KiB
  for (int i = threadIdx.x; i < CDIM * CDIM / 4; i += 256)
    reinterpret_cast<float4*>(w3s)[i] = reinterpret_cast<const float4*>(W3)[i];
  __syncthreads();

  const int b = blockIdx.x >> 8;
  const int ib = blockIdx.x & 255;
  const int wave = threadIdx.x >> 6;
  const int lane = threadIdx.x & 63;
  const int c0 = 2 * lane;

  float2 gpv = *(const float2*)&gproj[b * CDIM + c0];
  float2 b3v = *(const float2*)&b3[c0];
  float2 g3v = *(const float2*)&g3[c0];
  float2 be3v = *(const float2*)&be3[c0];
  float2 w4v = *(const float2*)&W4[c0];

  float dacc = 0.f;  // lanes 0..3 accumulate mask[v]*w

  for (int n = ib * 4 + wave; n < NPTS; n += 1024) {
    unsigned pk = *reinterpret_cast<const unsigned*>(
        &localw[(size_t)(b * NPTS + n) * CDIM + c0]);
    float l0 = bf2f((unsigned short)(pk & 0xFFFFu));
    float l1 = bf2f((unsigned short)(pk >> 16));
    float a0 = gpv.x + b3v.x, a1 = gpv.y + b3v.y;
#pragma unroll 8
    for (int j = 0; j < 64; ++j) {
      float lk0 = __shfl(l0, j);
      float lk1 = __shfl(l1, j);
      float2 wA = *(const float2*)&w3s[(2 * j) * CDIM + c0];
      float2 wB = *(const float2*)&w3s[(2 * j + 1) * CDIM + c0];
      a0 += lk0 * wA.x + lk1 * wB.x;
      a1 += lk0 * wA.y + lk1 * wB.y;
    }
    float T1 = wredsum(a0 + a1);
    float T2 = wredsum(a0 * a0 + a1 * a1);
    float mu = T1 * (1.f / 128.f);
    float var = T2 * (1.f / 128.f) - mu * mu;
    float rs = rsqrtf(var + 1e-5f);
    float h20 = fmaxf(0.f, (a0 - mu) * rs * g3v.x + be3v.x);
    float h21 = fmaxf(0.f, (a1 - mu) * rs * g3v.y + be3v.y);
    float U = wredsum(h20 * w4v.x + h21 * w4v.y);
    float w = 2.f / (1.f + expf(-U));
    if (lane == 0) w_arr[b * NPTS + n] = w;
    float mval = (lane < 4) ? masks[(b * 4 + lane) * NPTS + n] : 0.f;
    dacc += mval * w;
  }

  __syncthreads();
  float* red = w3s;  // reuse
  if (lane < 4) red[wave * 4 + lane] = dacc;
  __syncthreads();
  if (threadIdx.x < 4) {
    float s = red[threadIdx.x] + red[4 + threadIdx.x] + red[8 + threadIdx.x] +
              red[12 + threadIdx.x];
    atomicAdd(&denom[b * 4 + threadIdx.x], s);
  }
}

// pooling: out[b,v,c] = sum_n mask[b,v,n]*w[b,n]*feat[b,c,n] / denom + global
__global__ __launch_bounds__(256) void k_pool(
    const float* __restrict__ feat, const float* __restrict__ masks,
    const float* __restrict__ w_arr, const float* __restrict__ denom,
    const float* __restrict__ globalv, float* __restrict__ out) {
  const int b = blockIdx.x >> 7, c = blockIdx.x & 127;
  const float* f = &feat[(size_t)(b * CDIM + c) * NPTS];
  const float* m0p = &masks[(b * 4 + 0) * NPTS];
  const float* m1p = &masks[(b * 4 + 1) * NPTS];
  const float* m2p = &masks[(b * 4 + 2) * NPTS];
  const float* m3p = &masks[(b * 4 + 3) * NPTS];
  const float* wp = &w_arr[b * NPTS];
  float a0 = 0.f, a1 = 0.f, a2 = 0.f, a3 = 0.f;
  for (int n = threadIdx.x; n < NPTS; n += 256) {
    float fw = f[n] * wp[n];
    a0 += m0p[n] * fw;
    a1 += m1p[n] * fw;
    a2 += m2p[n] * fw;
    a3 += m3p[n] * fw;
  }
  a0 = wredsum(a0);
  a1 = wredsum(a1);
  a2 = wredsum(a2);
  a3 = wredsum(a3);
  __shared__ float red[4][4];
  const int wave = threadIdx.x >> 6, lane = threadIdx.x & 63;
  if (lane == 0) {
    red[wave][0] = a0;
    red[wave][1] = a1;
    red[wave][2] = a2;
    red[wave][3] = a3;
  }
  __syncthreads();
  if (threadIdx.x == 0) {
#pragma unroll
    for (int v = 0; v < 4; ++v) {
      float s = red[0][v] + red[1][v] + red[2][v] + red[3][v];
      out[(b * 4 + v) * CDIM + c] =
          s / (denom[b * 4 + v] + 1e-8f) + globalv[b * CDIM + c];
    }
  }
}

extern "C" void kernel_launch(void* const* d_in, const int* in_sizes, int n_in,
                              void* d_out, int out_size, void* d_ws,
                              size_t ws_size, hipStream_t stream) {
  const float* xyz = (const float*)d_in[0];
  const float* feat = (const float*)d_in[1];
  const float* masks = (const float*)d_in[2];
  const float* W1 = (const float*)d_in[3];
  const float* b1 = (const float*)d_in[4];
  const float* g1 = (const float*)d_in[5];
  const float* be1 = (const float*)d_in[6];
  const float* W2 = (const float*)d_in[7];
  const float* b2 = (const float*)d_in[8];
  const float* g2 = (const float*)d_in[9];
  const float* be2 = (const float*)d_in[10];
  const float* W3 = (const float*)d_in[11];
  const float* b3 = (const float*)d_in[12];
  const float* g3 = (const float*)d_in[13];
  const float* be3 = (const float*)d_in[14];
  const float* W4 = (const float*)d_in[15];
  float* out = (float*)d_out;

  char* ws = (char*)d_ws;
  unsigned* gkey = (unsigned*)ws;              // 512 u32   @ 0
  float* globalv = (float*)(ws + 2048);        // 512 f     @ 2048
  float* gproj = (float*)(ws + 4096);          // 512 f     @ 4096
  float* denom = (float*)(ws + 6144);          // 16 f      @ 6144
  float* w_arr = (float*)(ws + 8192);          // 160000 f  @ 8192
  unsigned short* localw = (unsigned short*)(ws + 651264);  // 40.96 MB bf16

  k_init<<<1, 512, 0, stream>>>(gkey, denom);
  k_phase1<<<1024, 256, 0, stream>>>(xyz, W1, b1, g1, be1, W2, b2, g2, be2,
                                     gkey, localw);
  k_global<<<1, 512, 0, stream>>>(gkey, W3, globalv, gproj);
  k_phase2<<<1024, 256, 0, stream>>>(localw, gproj, W3, b3, g3, be3, W4, masks,
                                     w_arr, denom);
  k_pool<<<512, 256, 0, stream>>>(feat, masks, w_arr, denom, globalv, out);
}

// Round 2
// 228.591 us; speedup vs baseline: 3.9905x; 3.9905x over previous
//
#include <hip/hip_runtime.h>
#include <stdint.h>

// GeoAwarePooling B=4, N=40000, C=128, V=4.
// xyz broadcast across views -> per-point MLP runs once over B*N points.
// All GEMMs via mfma_f32_16x16x32_bf16 in transposed form D[c][pt] so that
// LayerNorm reductions are in-lane + 2 shfl_xor.

#define NPTS 40000
#define CD   128
#define LDK  136   // padded bf16 row stride (16B-aligned k offsets)
#define SPLIT 128  // blocks per batch for MLP kernels

typedef __attribute__((ext_vector_type(8))) short bf8_t;
typedef __attribute__((ext_vector_type(4))) float f4_t;

__device__ __forceinline__ unsigned short f2bfu(float f){
  unsigned u = __float_as_uint(f);
  u += 0x7FFFu + ((u>>16)&1u);               // RNE
  return (unsigned short)(u>>16);
}
__device__ __forceinline__ float bfhi_f(float f){   // f rounded to bf16, as f32
  return __uint_as_float(((unsigned)f2bfu(f))<<16);
}
__device__ __forceinline__ unsigned pk2(float a, float b){
  return (unsigned)f2bfu(a) | ((unsigned)f2bfu(b)<<16);
}
__device__ __forceinline__ float uplo(unsigned u){ return __uint_as_float(u<<16); }
__device__ __forceinline__ float uphi(unsigned u){ return __uint_as_float(u & 0xFFFF0000u); }
__device__ __forceinline__ unsigned fenc(float f){  // order-preserving key
  unsigned u = __float_as_uint(f);
  return (u & 0x80000000u) ? ~u : (u | 0x80000000u);
}
__device__ __forceinline__ float fdec(unsigned k){
  return (k & 0x80000000u) ? __uint_as_float(k & 0x7FFFFFFFu) : __uint_as_float(~k);
}
__device__ __forceinline__ bf8_t mkbf8(unsigned a,unsigned b,unsigned c,unsigned d){
  union{ bf8_t v; unsigned u[4]; } r;
  r.u[0]=a; r.u[1]=b; r.u[2]=c; r.u[3]=d;
  return r.v;
}

__global__ __launch_bounds__(256)
void k_init(unsigned* __restrict__ kmax, unsigned* __restrict__ kmin,
            float* __restrict__ denom, float* __restrict__ pool_acc){
  int t = blockIdx.x*256 + threadIdx.x;
  if (t < 512){ kmax[t] = 0u; kmin[t] = 0xFFFFFFFFu; }
  if (t < 16) denom[t] = 0.f;
  if (t < 2048) pool_acc[t] = 0.f;
}

// ---------------------------------------------------------------------------
// MLP kernel. PB=false: phase A (track z2 per-channel max/min).
//             PB=true : phase B (recompute + GEMM3 + weights -> mwT, denom).
// Per wave: 16-point tile. GEMM form: D[128 c][16 pt] = A[c][k] @ B[k][pt].
// A-frag: lane row=l&15 (c=16mt+m), k=32ks+8g+i. B-frag: col=l&15 (pt), same k.
// D: col=l&15 (pt), row=4g+r (+16mt)  => lane holds ONE point's channels.
// ---------------------------------------------------------------------------
template<bool PB>
__global__ __launch_bounds__(256)
void k_mlp(const float* __restrict__ xyz,
           const float* __restrict__ W1, const float* __restrict__ b1,
           const float* __restrict__ g1, const float* __restrict__ be1,
           const float* __restrict__ W2, const float* __restrict__ b2,
           const float* __restrict__ g2,
           const float* __restrict__ W3,
           const float* __restrict__ g3, const float* __restrict__ be3,
           const float* __restrict__ W4,
           const float* __restrict__ masks,
           const float* __restrict__ gcomb,
           unsigned* __restrict__ kmax, unsigned* __restrict__ kmin,
           unsigned short* __restrict__ mwT,
           float* __restrict__ denom)
{
  extern __shared__ char smem[];
  unsigned short* W2T = (unsigned short*)smem;                            // 128*136*2
  unsigned short* Hb  = (unsigned short*)(smem + CD*LDK*2) + (threadIdx.x>>6)*(16*LDK);
  unsigned short* W3T = (unsigned short*)(smem + CD*LDK*2 + 4*16*LDK*2);  // PB only

  const int b = blockIdx.x / SPLIT;
  const int s = blockIdx.x % SPLIT;
  const int wave = threadIdx.x>>6, lane = threadIdx.x&63;
  const int m = lane&15, g = lane>>4;

  for (int idx = threadIdx.x; idx < CD*CD; idx += 256){
    int k = idx>>7, c = idx&127;
    W2T[c*LDK+k] = f2bfu(W2[idx]);
  }
  if (PB){
    for (int idx = threadIdx.x; idx < CD*CD; idx += 256){
      int k = idx>>7, c = idx&127;
      W3T[c*LDK+k] = f2bfu(g2[k]*W3[idx]);          // fold g2 into W3top rows
    }
  }
  __syncthreads();

  // layer-1 A-fragments (W1,b1 hi/lo split; k-slots:
  //  j0-2: W1h*xh  j3-5: W1h*xl  j6-8: W1l*xh  j9: b1h*1  j10: b1l*1)
  bf8_t A1[8];
#pragma unroll
  for (int mt=0; mt<8; ++mt){
    int c = 16*mt + m;
    float w0=W1[c], w1=W1[CD+c], w2=W1[2*CD+c], bb=b1[c];
    unsigned u0=0,u1=0,u2=0,u3=0;
    if (g==0){
      u0 = pk2(w0,w1);
      u1 = pk2(w2,w0);
      u2 = pk2(w1,w2);
      u3 = pk2(w0-bfhi_f(w0), w1-bfhi_f(w1));
    } else if (g==1){
      u0 = pk2(w2-bfhi_f(w2), bb);
      u1 = pk2(bb-bfhi_f(bb), 0.f);
    }
    A1[mt] = mkbf8(u0,u1,u2,u3);
  }

  // per-lane affine params for channels c(mt,r)=16mt+4g+r, bf16-packed
  unsigned g1p[16], be1p[16], b2p[16];
#pragma unroll
  for (int j=0;j<16;++j){
    int i0=2*j, i1=2*j+1;
    int c0 = 16*(i0>>2) + 4*g + (i0&3);
    int c1 = 16*(i1>>2) + 4*g + (i1&3);
    g1p[j]  = pk2(g1[c0],  g1[c1]);
    be1p[j] = pk2(be1[c0], be1[c1]);
    b2p[j]  = pk2(b2[c0],  b2[c1]);
  }

  float gcv[32];
  unsigned g3p[16], be3p[16], w4p[16];
  if (PB){
#pragma unroll
    for (int j=0;j<16;++j){
      int i0=2*j, i1=2*j+1;
      int c0 = 16*(i0>>2) + 4*g + (i0&3);
      int c1 = 16*(i1>>2) + 4*g + (i1&3);
      g3p[j]  = pk2(g3[c0],  g3[c1]);
      be3p[j] = pk2(be3[c0], be3[c1]);
      w4p[j]  = pk2(W4[c0],  W4[c1]);
      gcv[i0] = gcomb[b*CD + c0];
      gcv[i1] = gcomb[b*CD + c1];
    }
  }

  float zmx[8][4], zmn[8][4];
  if (!PB){
#pragma unroll
    for (int mt=0;mt<8;++mt)
#pragma unroll
      for (int r=0;r<4;++r){ zmx[mt][r] = -1e30f; zmn[mt][r] = 1e30f; }
  }
  float dacc = 0.f;

  for (int t = s*4 + wave; t < 2500; t += SPLIT*4){
    const int n = t*16 + m;
    float px = xyz[(3*b+0)*NPTS + n];
    float py = xyz[(3*b+1)*NPTS + n];
    float pz = xyz[(3*b+2)*NPTS + n];
    bf8_t B1;
    {
      unsigned u0=0,u1=0,u2=0,u3=0;
      if (g==0){
        u0 = pk2(px,py);
        u1 = pk2(pz, px-bfhi_f(px));
        u2 = pk2(py-bfhi_f(py), pz-bfhi_f(pz));
        u3 = pk2(px,py);
      } else if (g==1){
        u0 = pk2(pz, 1.0f);
        u1 = pk2(1.0f, 0.f);
      }
      B1 = mkbf8(u0,u1,u2,u3);
    }
    f4_t acc[8];
#pragma unroll
    for (int mt=0;mt<8;++mt)
      acc[mt] = __builtin_amdgcn_mfma_f32_16x16x32_bf16(A1[mt], B1, (f4_t){0.f,0.f,0.f,0.f}, 0,0,0);

    // LN1 (+ affine + relu) -> H bf16
    float s1=0.f, s2=0.f;
#pragma unroll
    for (int mt=0;mt<8;++mt)
#pragma unroll
      for (int r=0;r<4;++r){ float v=acc[mt][r]; s1+=v; s2+=v*v; }
    s1 += __shfl_xor(s1,16); s1 += __shfl_xor(s1,32);
    s2 += __shfl_xor(s2,16); s2 += __shfl_xor(s2,32);
    float mu = s1*(1.f/128.f);
    float rs = rsqrtf(fmaxf(s2*(1.f/128.f)-mu*mu,0.f)+1e-5f);
#pragma unroll
    for (int mt=0;mt<8;++mt){
      unsigned gA=g1p[2*mt], gB=g1p[2*mt+1], bA=be1p[2*mt], bB=be1p[2*mt+1];
      float h0 = fmaxf(0.f, fmaf((acc[mt][0]-mu)*rs, uplo(gA), uplo(bA)));
      float h1v= fmaxf(0.f, fmaf((acc[mt][1]-mu)*rs, uphi(gA), uphi(bA)));
      float h2v= fmaxf(0.f, fmaf((acc[mt][2]-mu)*rs, uplo(gB), uplo(bB)));
      float h3v= fmaxf(0.f, fmaf((acc[mt][3]-mu)*rs, uphi(gB), uphi(bB)));
      uint2 wv; wv.x = pk2(h0,h1v); wv.y = pk2(h2v,h3v);
      *reinterpret_cast<uint2*>(&Hb[m*LDK + 16*mt + 4*g]) = wv;
    }

    // GEMM2: a2 = h @ W2 (transposed form), wave-private Hb (in-order DS)
    f4_t a2[8];
#pragma unroll
    for (int mt=0;mt<8;++mt) a2[mt]=(f4_t){0.f,0.f,0.f,0.f};
#pragma unroll
    for (int ks=0;ks<4;++ks){
      bf8_t Bf = *reinterpret_cast<const bf8_t*>(&Hb[m*LDK + 32*ks + 8*g]);
#pragma unroll
      for (int mt=0;mt<8;++mt){
        bf8_t Af = *reinterpret_cast<const bf8_t*>(&W2T[(16*mt+m)*LDK + 32*ks + 8*g]);
        a2[mt] = __builtin_amdgcn_mfma_f32_16x16x32_bf16(Af, Bf, a2[mt], 0,0,0);
      }
    }
    // +b2, LN2 -> z2 (pre-affine; g2/be2 folded downstream)
    s1=0.f; s2=0.f;
#pragma unroll
    for (int mt=0;mt<8;++mt){
      unsigned bA=b2p[2*mt], bB=b2p[2*mt+1];
      acc[mt][0] = a2[mt][0]+uplo(bA);
      acc[mt][1] = a2[mt][1]+uphi(bA);
      acc[mt][2] = a2[mt][2]+uplo(bB);
      acc[mt][3] = a2[mt][3]+uphi(bB);
#pragma unroll
      for (int r=0;r<4;++r){ float v=acc[mt][r]; s1+=v; s2+=v*v; }
    }
    s1 += __shfl_xor(s1,16); s1 += __shfl_xor(s1,32);
    s2 += __shfl_xor(s2,16); s2 += __shfl_xor(s2,32);
    mu = s1*(1.f/128.f);
    rs = rsqrtf(fmaxf(s2*(1.f/128.f)-mu*mu,0.f)+1e-5f);

    if (!PB){
#pragma unroll
      for (int mt=0;mt<8;++mt)
#pragma unroll
        for (int r=0;r<4;++r){
          float z=(acc[mt][r]-mu)*rs;
          zmx[mt][r]=fmaxf(zmx[mt][r],z);
          zmn[mt][r]=fminf(zmn[mt][r],z);
        }
    } else {
#pragma unroll
      for (int mt=0;mt<8;++mt){
        float z0=(acc[mt][0]-mu)*rs, z1=(acc[mt][1]-mu)*rs;
        float z2v=(acc[mt][2]-mu)*rs, z3=(acc[mt][3]-mu)*rs;
        uint2 wv; wv.x=pk2(z0,z1); wv.y=pk2(z2v,z3);
        *reinterpret_cast<uint2*>(&Hb[m*LDK + 16*mt + 4*g]) = wv;
      }
      // GEMM3: u = z2 @ (g2*W3top)  (+ gcomb = b3 + be2@W3top + global@W3bot)
      f4_t a3[8];
#pragma unroll
      for (int mt=0;mt<8;++mt) a3[mt]=(f4_t){0.f,0.f,0.f,0.f};
#pragma unroll
      for (int ks=0;ks<4;++ks){
        bf8_t Bf = *reinterpret_cast<const bf8_t*>(&Hb[m*LDK + 32*ks + 8*g]);
#pragma unroll
        for (int mt=0;mt<8;++mt){
          bf8_t Af = *reinterpret_cast<const bf8_t*>(&W3T[(16*mt+m)*LDK + 32*ks + 8*g]);
          a3[mt] = __builtin_amdgcn_mfma_f32_16x16x32_bf16(Af, Bf, a3[mt], 0,0,0);
        }
      }
      s1=0.f; s2=0.f;
#pragma unroll
      for (int mt=0;mt<8;++mt)
#pragma unroll
        for (int r=0;r<4;++r){ float v = a3[mt][r] + gcv[mt*4+r]; acc[mt][r]=v; s1+=v; s2+=v*v; }
      s1 += __shfl_xor(s1,16); s1 += __shfl_xor(s1,32);
      s2 += __shfl_xor(s2,16); s2 += __shfl_xor(s2,32);
      float mu3 = s1*(1.f/128.f);
      float rs3 = rsqrtf(fmaxf(s2*(1.f/128.f)-mu3*mu3,0.f)+1e-5f);
      float U = 0.f;
#pragma unroll
      for (int mt=0;mt<8;++mt){
        unsigned gA=g3p[2*mt], gB=g3p[2*mt+1];
        unsigned bA=be3p[2*mt], bB=be3p[2*mt+1];
        unsigned wA=w4p[2*mt], wB=w4p[2*mt+1];
        float h0 = fmaxf(0.f, fmaf((acc[mt][0]-mu3)*rs3, uplo(gA), uplo(bA)));
        float h1v= fmaxf(0.f, fmaf((acc[mt][1]-mu3)*rs3, uphi(gA), uphi(bA)));
        float h2v= fmaxf(0.f, fmaf((acc[mt][2]-mu3)*rs3, uplo(gB), uplo(bB)));
        float h3v= fmaxf(0.f, fmaf((acc[mt][3]-mu3)*rs3, uphi(gB), uphi(bB)));
        U = fmaf(h0, uplo(wA), U);
        U = fmaf(h1v, uphi(wA), U);
        U = fmaf(h2v, uplo(wB), U);
        U = fmaf(h3v, uphi(wB), U);
      }
      U += __shfl_xor(U,16); U += __shfl_xor(U,32);
      float w = 2.f/(1.f + __expf(-U));
      float msk = masks[(size_t)(4*b+g)*NPTS + n];
      mwT[(size_t)(b*16+g)*NPTS + n] = f2bfu(msk*w);
      dacc += msk*w;
    }
  }

  if (!PB){
#pragma unroll
    for (int mt=0;mt<8;++mt)
#pragma unroll
      for (int r=0;r<4;++r){
        float vx = zmx[mt][r], vn = zmn[mt][r];
        vx = fmaxf(vx, __shfl_xor(vx,1)); vx = fmaxf(vx, __shfl_xor(vx,2));
        vx = fmaxf(vx, __shfl_xor(vx,4)); vx = fmaxf(vx, __shfl_xor(vx,8));
        vn = fminf(vn, __shfl_xor(vn,1)); vn = fminf(vn, __shfl_xor(vn,2));
        vn = fminf(vn, __shfl_xor(vn,4)); vn = fminf(vn, __shfl_xor(vn,8));
        if (m==0){
          int c = 16*mt + 4*g + r;
          atomicMax(&kmax[b*CD+c], fenc(vx));
          atomicMin(&kmin[b*CD+c], fenc(vn));
        }
      }
  } else {
    dacc += __shfl_xor(dacc,1); dacc += __shfl_xor(dacc,2);
    dacc += __shfl_xor(dacc,4); dacc += __shfl_xor(dacc,8);
    if (m==0) atomicAdd(&denom[b*4+g], dacc);
  }
}

// global[b][c] from max/min keys (+affine2), gcomb = b3 + be2@W3top + global@W3bot
__global__ __launch_bounds__(256)
void k_global(const unsigned* __restrict__ kmax, const unsigned* __restrict__ kmin,
              const float* __restrict__ g2, const float* __restrict__ be2,
              const float* __restrict__ W3, const float* __restrict__ b3,
              float* __restrict__ globalv, float* __restrict__ gcomb)
{
  __shared__ float gs[128], bs[128], part[256];
  int b = blockIdx.x;
  int t = threadIdx.x;
  if (t < 128){
    float gg = g2[t];
    float zx = fdec(kmax[b*CD+t]), zn = fdec(kmin[b*CD+t]);
    float gl = (gg>=0.f ? gg*zx : gg*zn) + be2[t];
    gs[t] = gl;
    globalv[b*CD+t] = gl;
    bs[t] = be2[t];
  }
  __syncthreads();
  int c = t & 127, half = t >> 7;
  float accv = 0.f;
  if (half==0){
    for (int k=0;k<128;++k) accv = fmaf(bs[k], W3[k*CD+c], accv);
    accv += b3[c];
  } else {
    for (int k=0;k<128;++k) accv = fmaf(gs[k], W3[(128+k)*CD+c], accv);
  }
  part[t] = accv;
  __syncthreads();
  if (half==0) gcomb[b*CD+c] = part[c] + part[128+c];
}

// pooled[c][v] = sum_n feat[c][n] * mwT[v][n]   (MFMA, feat streamed once)
__global__ __launch_bounds__(256)
void k_pool(const float* __restrict__ feat, const unsigned short* __restrict__ mwT,
            float* __restrict__ pool_acc)
{
  int b = blockIdx.x / 125, s = blockIdx.x % 125;
  int wave = threadIdx.x>>6, lane = threadIdx.x&63;
  int m = lane&15, g = lane>>4;
  int mt0 = 2*wave, mt1 = 2*wave+1;
  f4_t p0 = {0.f,0.f,0.f,0.f}, p1 = {0.f,0.f,0.f,0.f};
  const size_t fb = (size_t)b*CD*NPTS;
  for (int kk=0;kk<10;++kk){
    int nb = (s*10+kk)*32 + 8*g;
    bf8_t Bf = *reinterpret_cast<const bf8_t*>(&mwT[(size_t)(b*16+m)*NPTS + nb]);
    const float* fA = &feat[fb + (size_t)(16*mt0+m)*NPTS + nb];
    f4_t x0 = *reinterpret_cast<const f4_t*>(fA);
    f4_t x1 = *reinterpret_cast<const f4_t*>(fA+4);
    bf8_t Af0 = mkbf8(pk2(x0[0],x0[1]),pk2(x0[2],x0[3]),pk2(x1[0],x1[1]),pk2(x1[2],x1[3]));
    p0 = __builtin_amdgcn_mfma_f32_16x16x32_bf16(Af0, Bf, p0, 0,0,0);
    const float* fB = &feat[fb + (size_t)(16*mt1+m)*NPTS + nb];
    f4_t y0 = *reinterpret_cast<const f4_t*>(fB);
    f4_t y1 = *reinterpret_cast<const f4_t*>(fB+4);
    bf8_t Af1 = mkbf8(pk2(y0[0],y0[1]),pk2(y0[2],y0[3]),pk2(y1[0],y1[1]),pk2(y1[2],y1[3]));
    p1 = __builtin_amdgcn_mfma_f32_16x16x32_bf16(Af1, Bf, p1, 0,0,0);
  }
  if (m < 4){
#pragma unroll
    for (int r=0;r<4;++r){
      atomicAdd(&pool_acc[(b*4+m)*CD + 16*mt0+4*g+r], p0[r]);
      atomicAdd(&pool_acc[(b*4+m)*CD + 16*mt1+4*g+r], p1[r]);
    }
  }
}

__global__ __launch_bounds__(256)
void k_final(const float* __restrict__ pool_acc, const float* __restrict__ denom,
             const float* __restrict__ globalv, float* __restrict__ out)
{
  int t = blockIdx.x*256 + threadIdx.x;   // 2048
  int bv = t>>7, c = t&127, b = bv>>2;
  out[t] = pool_acc[t]/(denom[bv]+1e-8f) + globalv[b*CD+c];
}

extern "C" void kernel_launch(void* const* d_in, const int* in_sizes, int n_in,
                              void* d_out, int out_size, void* d_ws,
                              size_t ws_size, hipStream_t stream) {
  const float* xyz  = (const float*)d_in[0];
  const float* feat = (const float*)d_in[1];
  const float* masks= (const float*)d_in[2];
  const float* W1 = (const float*)d_in[3];
  const float* b1 = (const float*)d_in[4];
  const float* g1 = (const float*)d_in[5];
  const float* be1= (const float*)d_in[6];
  const float* W2 = (const float*)d_in[7];
  const float* b2 = (const float*)d_in[8];
  const float* g2 = (const float*)d_in[9];
  const float* be2= (const float*)d_in[10];
  const float* W3 = (const float*)d_in[11];
  const float* b3 = (const float*)d_in[12];
  const float* g3 = (const float*)d_in[13];
  const float* be3= (const float*)d_in[14];
  const float* W4 = (const float*)d_in[15];
  float* out = (float*)d_out;

  char* ws = (char*)d_ws;
  unsigned* kmax    = (unsigned*)ws;                 // 512 u32
  unsigned* kmin    = (unsigned*)(ws + 2048);        // 512 u32
  float*    denom   = (float*)(ws + 4096);           // 16 f
  float*    pool_acc= (float*)(ws + 4160);           // 2048 f
  float*    globalv = (float*)(ws + 12352);          // 512 f
  float*    gcomb   = (float*)(ws + 14400);          // 512 f
  unsigned short* mwT = (unsigned short*)(ws + 16448); // 4*16*40000 bf16

  const int smemA = CD*LDK*2 + 4*16*LDK*2;           // 52224
  const int smemB = smemA + CD*LDK*2;                // 87040

  auto kb = k_mlp<true>;
  hipFuncSetAttribute(reinterpret_cast<const void*>(kb),
                      hipFuncAttributeMaxDynamicSharedMemorySize, 98304);

  k_init<<<16, 256, 0, stream>>>(kmax, kmin, denom, pool_acc);
  k_mlp<false><<<4*SPLIT, 256, smemA, stream>>>(xyz, W1, b1, g1, be1, W2, b2, g2,
                                                W3, g3, be3, W4, masks, gcomb,
                                                kmax, kmin, mwT, denom);
  k_global<<<4, 256, 0, stream>>>(kmax, kmin, g2, be2, W3, b3, globalv, gcomb);
  k_mlp<true><<<4*SPLIT, 256, smemB, stream>>>(xyz, W1, b1, g1, be1, W2, b2, g2,
                                               W3, g3, be3, W4, masks, gcomb,
                                               kmax, kmin, mwT, denom);
  k_pool<<<500, 256, 0, stream>>>(feat, mwT, pool_acc);
  k_final<<<8, 256, 0, stream>>>(pool_acc, denom, globalv, out);
}